// Round 4
// baseline (247.095 us; speedup 1.0000x reference)
//
#include <hip/hip_runtime.h>
#include <hip/hip_fp16.h>

#define USER_NUM 80000
#define ITEM_NUM 40000
#define NNODE (USER_NUM + ITEM_NUM)
#define EMB 64
#define NB 469            // ceil(NNODE / 256) buckets of 256 rows
#define P1_CHUNK 4096
#define SPMM_BLOCKS 2048  // 8 blocks/CU * 256 CUs: fills the chip exactly

// fp16 intermediate scaling: typical y ~ 1e-4 would be fp16-denormal; scale by
// 2^13 (exact) so stored magnitudes land in the normal range. Max |x|*S ~ 71.
#define HSCALE 8192.0f
#define HINV   (1.0f / 8192.0f)

// ===========================================================================
// Step 0: convert fp32 embeddings -> scaled fp16 table x0h (concat user|item).
// Makes layer 1's gather identical to layers 2/3: 128B rows = 1 L2
// transaction per edge instead of 2.
// ===========================================================================
__global__ void convert_kernel(const float* __restrict__ ue, const float* __restrict__ ie,
                               ushort* __restrict__ x0h) {
    int idx = blockIdx.x * blockDim.x + threadIdx.x;   // one thread = 8 floats
    const int total = NNODE * EMB / 8;
    if (idx >= total) return;
    const int utotal = USER_NUM * EMB / 8;
    const float4* src = (idx < utotal) ? ((const float4*)ue) + 2 * (size_t)idx
                                       : ((const float4*)ie) + 2 * (size_t)(idx - utotal);
    float4 a = src[0], b = src[1];
    __half2 h0 = __floats2half2_rn(a.x * HSCALE, a.y * HSCALE);
    __half2 h1 = __floats2half2_rn(a.z * HSCALE, a.w * HSCALE);
    __half2 h2 = __floats2half2_rn(b.x * HSCALE, b.y * HSCALE);
    __half2 h3 = __floats2half2_rn(b.z * HSCALE, b.w * HSCALE);
    uint4 pk = make_uint4(*(const unsigned*)&h0, *(const unsigned*)&h1,
                          *(const unsigned*)&h2, *(const unsigned*)&h3);
    ((uint4*)x0h)[idx] = pk;
}

// ===========================================================================
// Build step 1: coarse histogram of row>>8 (LDS-aggregated, int4 loads)
// ===========================================================================
__global__ void bucket_hist_kernel(const int* __restrict__ rows, int* __restrict__ bcounts, int nnz) {
    __shared__ int h[NB];
    for (int i = threadIdx.x; i < NB; i += blockDim.x) h[i] = 0;
    __syncthreads();
    int nq = nnz >> 2;
    int stride = gridDim.x * blockDim.x;
    for (int i = blockIdx.x * blockDim.x + threadIdx.x; i < nq; i += stride) {
        int4 r = ((const int4*)rows)[i];
        atomicAdd(&h[r.x >> 8], 1);
        atomicAdd(&h[r.y >> 8], 1);
        atomicAdd(&h[r.z >> 8], 1);
        atomicAdd(&h[r.w >> 8], 1);
    }
    if (blockIdx.x == 0) {
        for (int i = (nq << 2) + threadIdx.x; i < nnz; i += blockDim.x)
            atomicAdd(&h[rows[i] >> 8], 1);
    }
    __syncthreads();
    for (int i = threadIdx.x; i < NB; i += blockDim.x)
        if (h[i]) atomicAdd(&bcounts[i], h[i]);
}

// ===========================================================================
// Build step 2: exclusive scan of 469 bucket counts (single block)
// ===========================================================================
__global__ void bucket_scan_kernel(const int* __restrict__ bcounts, int* __restrict__ bucket_off,
                                   int* __restrict__ bcursor, int* __restrict__ row_ptr, int nnz) {
    __shared__ int lds[512];
    int t = threadIdx.x;
    int v = (t < NB) ? bcounts[t] : 0;
    lds[t] = v;
    __syncthreads();
    for (int off = 1; off < 512; off <<= 1) {
        int add = (t >= off) ? lds[t - off] : 0;
        __syncthreads();
        lds[t] += add;
        __syncthreads();
    }
    if (t < NB) {
        int ex = lds[t] - v;
        bucket_off[t] = ex;
        bcursor[t]    = ex;
    }
    if (t == 0) { bucket_off[NB] = nnz; row_ptr[NNODE] = nnz; }
}

// ===========================================================================
// Build step 3: bin edges into buckets (one global atomic per block,bucket;
// sequential line-friendly writes). Vectorized int4/float4 input reads.
// tmp packs {col | row_local<<17, val_bits}.
// ===========================================================================
__global__ void phase1_kernel(const int* __restrict__ rows, const int* __restrict__ cols,
                              const float* __restrict__ vals, int* __restrict__ bcursor,
                              int2* __restrict__ tmp, int nnz) {
    __shared__ int h[NB];
    __shared__ int base[NB];
    int t = threadIdx.x;
    for (int i = t; i < NB; i += 256) h[i] = 0;
    __syncthreads();
    int lo = blockIdx.x * P1_CHUNK;
    int hi = lo + P1_CHUNK; if (hi > nnz) hi = nnz;
    int n4 = (hi - lo) >> 2;                    // lo is 16B-aligned (P1_CHUNK%4==0)
    const int4*   rows4 = (const int4*)(rows + lo);
    const int4*   cols4 = (const int4*)(cols + lo);
    const float4* vals4 = (const float4*)(vals + lo);

    for (int i = t; i < n4; i += 256) {
        int4 r = rows4[i];
        atomicAdd(&h[r.x >> 8], 1);
        atomicAdd(&h[r.y >> 8], 1);
        atomicAdd(&h[r.z >> 8], 1);
        atomicAdd(&h[r.w >> 8], 1);
    }
    for (int i = lo + (n4 << 2) + t; i < hi; i += 256)
        atomicAdd(&h[rows[i] >> 8], 1);
    __syncthreads();
    for (int i = t; i < NB; i += 256) {
        int c = h[i];
        base[i] = c ? atomicAdd(&bcursor[i], c) : 0;
        h[i] = 0;
    }
    __syncthreads();
    for (int i = t; i < n4; i += 256) {
        int4 r = rows4[i];
        int4 c = cols4[i];
        float4 v = vals4[i];
        {
            int b = r.x >> 8; int loc = atomicAdd(&h[b], 1);
            tmp[base[b] + loc] = make_int2(c.x | ((r.x & 255) << 17), __float_as_int(v.x));
        }
        {
            int b = r.y >> 8; int loc = atomicAdd(&h[b], 1);
            tmp[base[b] + loc] = make_int2(c.y | ((r.y & 255) << 17), __float_as_int(v.y));
        }
        {
            int b = r.z >> 8; int loc = atomicAdd(&h[b], 1);
            tmp[base[b] + loc] = make_int2(c.z | ((r.z & 255) << 17), __float_as_int(v.z));
        }
        {
            int b = r.w >> 8; int loc = atomicAdd(&h[b], 1);
            tmp[base[b] + loc] = make_int2(c.w | ((r.w & 255) << 17), __float_as_int(v.w));
        }
    }
    for (int i = lo + (n4 << 2) + t; i < hi; i += 256) {
        int r = rows[i];
        int b = r >> 8;
        int loc = atomicAdd(&h[b], 1);
        tmp[base[b] + loc] = make_int2(cols[i] | ((r & 255) << 17), __float_as_int(vals[i]));
    }
}

// ===========================================================================
// Build step 4: one block per bucket, exact per-row counts + scan -> row_ptr;
// LDS cursors place edges into final CSR.
// ===========================================================================
__global__ void phase2_kernel(const int2* __restrict__ tmp, const int* __restrict__ bucket_off,
                              int* __restrict__ row_ptr, int2* __restrict__ edges) {
    __shared__ int hist[256];
    __shared__ int scan[256];
    __shared__ int cur[256];
    int b = blockIdx.x;
    int t = threadIdx.x;
    int row0  = b << 8;
    int nrows = NNODE - row0; if (nrows > 256) nrows = 256;
    int start = bucket_off[b];
    int end   = bucket_off[b + 1];
    hist[t] = 0;
    __syncthreads();
    for (int j = start + t; j < end; j += 256)
        atomicAdd(&hist[tmp[j].x >> 17], 1);
    __syncthreads();
    int v = hist[t];
    scan[t] = v;
    __syncthreads();
    for (int off = 1; off < 256; off <<= 1) {
        int add = (t >= off) ? scan[t - off] : 0;
        __syncthreads();
        scan[t] += add;
        __syncthreads();
    }
    int ex = scan[t] - v + start;   // exclusive prefix + bucket base
    if (t < nrows) row_ptr[row0 + t] = ex;
    cur[t] = ex;
    __syncthreads();
    for (int j = start + t; j < end; j += 256) {
        int2 e  = tmp[j];
        int rl  = e.x >> 17;
        int pos = atomicAdd(&cur[rl], 1);
        edges[pos] = make_int2(e.x & 0x1FFFF, e.y);
    }
}

// ===========================================================================
// CSR SpMM (all layers fp16-gather, 128B rows = 1 L2 transaction per edge):
// PERSISTENT waves: 2048 blocks (8/CU), each wave grid-strides over the
// 30000 wave-tasks (4 rows each). The NEXT task's row_ptr quintet is
// prefetched at the top of each iteration so its latency hides under the
// current task's edge-loads and gathers (it is the oldest outstanding VMEM
// op, so counted vmcnt waits on the gathers retire it first for free).
// Lane layout per task: group g (16 lanes) owns row r0+g; lane c=(lane&15)
// holds dims [4c,4c+4). Gathered values pre-scaled by HSCALE.
//   non-FINAL: write acc packed to scaled fp16.
//   FINAL:     gather y2h; read own-row y1h+y2h sequentially;
//              out = (y1h + y2h + acc) * HINV / 3 (single fp32 write pass).
// ===========================================================================
__device__ __forceinline__ void load16(long long ev[16], const int2* __restrict__ edges,
                                       int sg, int eg, int j) {
    #pragma unroll
    for (int u = 0; u < 16; ++u) {
        int i = sg + j + u;
        ev[u] = (i < eg) ? *(const long long*)(edges + i) : 0LL;
    }
}

__device__ __forceinline__ float4 unpack_half4(uint2 gv) {
    float2 a = __half22float2(*(const __half2*)&gv.x);
    float2 b = __half22float2(*(const __half2*)&gv.y);
    return make_float4(a.x, a.y, b.x, b.y);
}

template <bool FINAL>
__launch_bounds__(256)
__global__ void spmm_kernel(const ushort* __restrict__ xh,
                            const int* __restrict__ row_ptr, const int2* __restrict__ edges,
                            ushort* __restrict__ yh,
                            const ushort* __restrict__ y1h_own, float* __restrict__ out) {
    const int lane = threadIdx.x & 63;
    const int g = lane >> 4;                   // which of the 4 rows
    const int c = lane & 15;                   // which uint2 chunk of the row
    const int NTASK  = NNODE >> 2;             // 30000 wave-tasks (NNODE%4==0)
    const int NWAVES = SPMM_BLOCKS * 4;        // resident wave count

    int wid = (blockIdx.x * blockDim.x + threadIdx.x) >> 6;

    // prime the rowptr pipeline for this wave's first task
    int rp_next = 0;
    if (wid < NTASK && lane < 5) rp_next = row_ptr[(wid << 2) + lane];

    for (int task = wid; task < NTASK; task += NWAVES) {
        int rp = rp_next;
        int nt = task + NWAVES;
        if (nt < NTASK && lane < 5) rp_next = row_ptr[(nt << 2) + lane];  // prefetch

        int p0 = __builtin_amdgcn_readlane(rp, 0);
        int p1 = __builtin_amdgcn_readlane(rp, 1);
        int p2 = __builtin_amdgcn_readlane(rp, 2);
        int p3 = __builtin_amdgcn_readlane(rp, 3);
        int p4 = __builtin_amdgcn_readlane(rp, 4);

        int sg = (g == 0) ? p0 : (g == 1) ? p1 : (g == 2) ? p2 : p3;   // row start
        int eg = (g == 0) ? p1 : (g == 1) ? p2 : (g == 2) ? p3 : p4;   // row end
        int maxd = max(max(p1 - p0, p2 - p1), max(p3 - p2, p4 - p3));  // wave bound

        float4 acc = make_float4(0.f, 0.f, 0.f, 0.f);

        for (int j = 0; j < maxd; j += 16) {
            long long ev[16];
            load16(ev, edges, sg, eg, j);
            #pragma unroll
            for (int u = 0; u < 16; ++u) {
                int   col = (int)(unsigned)ev[u];
                float v   = __int_as_float((int)(ev[u] >> 32));
                uint2 hv = ((const uint2*)(xh + (size_t)col * EMB))[c];
                float4 gv = unpack_half4(hv);
                acc.x += v * gv.x; acc.y += v * gv.y;
                acc.z += v * gv.z; acc.w += v * gv.w;
            }
        }

        int row = (task << 2) + g;
        size_t oh = (size_t)row * EMB + (size_t)c * 4;   // element offset

        if (!FINAL) {
            // acc is already scaled (gathered values were pre-scaled)
            __half2 h0 = __floats2half2_rn(acc.x, acc.y);
            __half2 h1 = __floats2half2_rn(acc.z, acc.w);
            uint2 pk = make_uint2(*(const unsigned*)&h0, *(const unsigned*)&h1);
            *(uint2*)(yh + oh) = pk;
        } else {
            // acc == y3 * HSCALE; own-row y1,y2 (scaled fp16) read sequentially
            uint2 o1 = *(const uint2*)(y1h_own + oh);
            uint2 o2 = *(const uint2*)(xh + oh);
            float4 y1v = unpack_half4(o1);
            float4 y2v = unpack_half4(o2);
            const float s = HINV / 3.0f;
            float4 t;
            t.x = (y1v.x + y2v.x + acc.x) * s;
            t.y = (y1v.y + y2v.y + acc.y) * s;
            t.z = (y1v.z + y2v.z + acc.z) * s;
            t.w = (y1v.w + y2v.w + acc.w) * s;
            *(float4*)(out + oh) = t;
        }
    }
}

// ===========================================================================
// Fallback (atomic path) in case ws_size is too small for CSR arrays
// ===========================================================================
__global__ void init_kernel(const float* __restrict__ user_emb, const float* __restrict__ item_emb,
                            float* __restrict__ x, float* __restrict__ out) {
    int idx = blockIdx.x * blockDim.x + threadIdx.x;
    const int total = NNODE * EMB / 4;
    if (idx >= total) return;
    const int user_total = USER_NUM * EMB / 4;
    float4 v = (idx < user_total) ? ((const float4*)user_emb)[idx]
                                  : ((const float4*)item_emb)[idx - user_total];
    ((float4*)x)[idx]   = v;
    ((float4*)out)[idx] = make_float4(0.f, 0.f, 0.f, 0.f);
}

__global__ void scatter_kernel(const float* __restrict__ x, float* __restrict__ y,
                               const float* __restrict__ vals, const int* __restrict__ rows,
                               const int* __restrict__ cols, int nnz) {
    int tid = blockIdx.x * blockDim.x + threadIdx.x;
    int e = tid >> 4;
    if (e >= nnz) return;
    int c = tid & 15;
    int r = rows[e], col = cols[e];
    float v = vals[e];
    float4 xv = ((const float4*)(x + (size_t)col * EMB))[c];
    float* dst = y + (size_t)r * EMB + (size_t)c * 4;
    atomicAdd(dst + 0, xv.x * v);
    atomicAdd(dst + 1, xv.y * v);
    atomicAdd(dst + 2, xv.z * v);
    atomicAdd(dst + 3, xv.w * v);
}

__global__ void accum_kernel(float* __restrict__ out, const float* __restrict__ y, float scale) {
    int idx = blockIdx.x * blockDim.x + threadIdx.x;
    const int total = NNODE * EMB / 4;
    if (idx >= total) return;
    float4 o = ((float4*)out)[idx];
    float4 a = ((const float4*)y)[idx];
    o.x = (o.x + a.x) * scale; o.y = (o.y + a.y) * scale;
    o.z = (o.z + a.z) * scale; o.w = (o.w + a.w) * scale;
    ((float4*)out)[idx] = o;
}

extern "C" void kernel_launch(void* const* d_in, const int* in_sizes, int n_in,
                              void* d_out, int out_size, void* d_ws, size_t ws_size,
                              hipStream_t stream) {
    const float* user_emb = (const float*)d_in[0];
    const float* item_emb = (const float*)d_in[1];
    const float* vals     = (const float*)d_in[2];
    const int*   rows     = (const int*)d_in[3];
    const int*   cols     = (const int*)d_in[4];
    const int    nnz      = in_sizes[2];

    float* out = (float*)d_out;

    const size_t embN   = (size_t)NNODE * EMB;        // 7,680,000 floats
    const size_t rp_pad = 120064;                     // NNODE+1 rounded up (8B-align after)

    // Persistent ws layout (unchanged footprint):
    //   bufA: embN floats | bufB: embN floats | row_ptr: rp_pad ints | edges: nnz int2
    // Build-time aliases (dead before their host buffer is written):
    //   tmp (nnz int2) -> front of bufA; bcounts/bucket_off/bcursor -> front of bufB
    // Runtime aliases:
    //   y1h (embN halves) + y2h (embN halves) occupy exactly bufA.
    //   x0h (embN halves) occupies the BACK half of bufB (clear of the 6KB
    //   build aliases at bufB's front and of row_ptr which starts after bufB).
    size_t need = (2 * embN + rp_pad) * 4 + (size_t)nnz * 8;

    if (ws_size >= need) {
        float* bufA    = (float*)d_ws;
        float* bufB    = bufA + embN;
        int*   row_ptr = (int*)(bufB + embN);
        int2*  edges   = (int2*)(row_ptr + rp_pad);

        int2* tmp        = (int2*)bufA;
        int*  bcounts    = (int*)bufB;
        int*  bucket_off = bcounts + 512;       // NB+1 used
        int*  bcursor    = bucket_off + 512;

        ushort* y1h = (ushort*)bufA;            // embN halves = 15.36 MB
        ushort* y2h = y1h + embN;               // 128B-aligned (embN*2 % 128 == 0)
        ushort* x0h = ((ushort*)bufB) + embN;   // back half of bufB, 15.36 MB

        // --- step 0: fp16 input table ---
        {
            int total = NNODE * EMB / 8;
            convert_kernel<<<(total + 255) / 256, 256, 0, stream>>>(user_emb, item_emb, x0h);
        }

        // --- build CSR (two-pass LDS-binned counting sort) ---
        hipMemsetAsync(bcounts, 0, NB * sizeof(int), stream);
        bucket_hist_kernel<<<256, 256, 0, stream>>>(rows, bcounts, nnz);
        bucket_scan_kernel<<<1, 512, 0, stream>>>(bcounts, bucket_off, bcursor, row_ptr, nnz);
        phase1_kernel<<<(nnz + P1_CHUNK - 1) / P1_CHUNK, 256, 0, stream>>>(rows, cols, vals, bcursor, tmp, nnz);
        phase2_kernel<<<NB, 256, 0, stream>>>(tmp, bucket_off, row_ptr, edges);

        // --- 3 propagation layers (persistent-wave fp16-gather kernels) ---
        const int nwaves_needed = NNODE / 4;                       // 30000 tasks
        int blocks = SPMM_BLOCKS;
        int max_blocks = (nwaves_needed * 64 + 255) / 256;
        if (blocks > max_blocks) blocks = max_blocks;
        spmm_kernel<false><<<blocks, 256, 0, stream>>>(x0h, row_ptr, edges, y1h, nullptr, nullptr);
        spmm_kernel<false><<<blocks, 256, 0, stream>>>(y1h, row_ptr, edges, y2h, nullptr, nullptr);
        spmm_kernel<true ><<<blocks, 256, 0, stream>>>(y2h, row_ptr, edges, nullptr, y1h, out);
    } else {
        // fallback: atomic scatter path
        float* x = (float*)d_ws;
        float* y = x + embN;
        const size_t emb_bytes = embN * sizeof(float);
        {
            int total = NNODE * EMB / 4;
            init_kernel<<<(total + 255) / 256, 256, 0, stream>>>(user_emb, item_emb, x, out);
        }
        for (int layer = 0; layer < 3; ++layer) {
            hipMemsetAsync(y, 0, emb_bytes, stream);
            long long threads = (long long)nnz * 16;
            scatter_kernel<<<(int)((threads + 255) / 256), 256, 0, stream>>>(x, y, vals, rows, cols, nnz);
            int total = NNODE * EMB / 4;
            accum_kernel<<<(total + 255) / 256, 256, 0, stream>>>(out, y, layer < 2 ? 1.0f : (1.0f / 3.0f));
            float* t = x; x = y; y = t;
        }
    }
}

// Round 5
// 224.228 us; speedup vs baseline: 1.1020x; 1.1020x over previous
//
#include <hip/hip_runtime.h>
#include <hip/hip_fp16.h>

#define USER_NUM 80000
#define ITEM_NUM 40000
#define NNODE (USER_NUM + ITEM_NUM)
#define EMB 64
#define NB 469            // ceil(NNODE / 256) buckets of 256 rows
#define P1_CHUNK 4096

// fp16 intermediate scaling: typical y ~ 1e-4 would be fp16-denormal; scale by
// 2^13 (exact) so stored magnitudes land in the normal range. Max |x|*S ~ 71.
#define HSCALE 8192.0f
#define HINV   (1.0f / 8192.0f)

// ===========================================================================
// Fused step 0 + build step 1 (independent jobs, disjoint block ranges):
//   blocks [0,256):   coarse histogram of row>>8 (LDS-aggregated, int4 loads)
//   blocks [256,...): convert fp32 embeddings -> scaled fp16 table x0h
// Overlaps the ~10us convert under the hist instead of serializing.
// ===========================================================================
#define CONV_ITEMS (NNODE * EMB / 8)                 // 960000 (8 floats/thread)
#define CONV_BLOCKS ((CONV_ITEMS + 255) / 256)       // 3750

__global__ void convhist_kernel(const float* __restrict__ ue, const float* __restrict__ ie,
                                ushort* __restrict__ x0h,
                                const int* __restrict__ rows, int* __restrict__ bcounts,
                                int nnz) {
    __shared__ int h[NB];
    if (blockIdx.x < 256) {
        // ---- histogram job ----
        for (int i = threadIdx.x; i < NB; i += 256) h[i] = 0;
        __syncthreads();
        int nq = nnz >> 2;
        int stride = 256 * 256;
        for (int i = blockIdx.x * 256 + threadIdx.x; i < nq; i += stride) {
            int4 r = ((const int4*)rows)[i];
            atomicAdd(&h[r.x >> 8], 1);
            atomicAdd(&h[r.y >> 8], 1);
            atomicAdd(&h[r.z >> 8], 1);
            atomicAdd(&h[r.w >> 8], 1);
        }
        if (blockIdx.x == 0) {
            for (int i = (nq << 2) + threadIdx.x; i < nnz; i += 256)
                atomicAdd(&h[rows[i] >> 8], 1);
        }
        __syncthreads();
        for (int i = threadIdx.x; i < NB; i += 256)
            if (h[i]) atomicAdd(&bcounts[i], h[i]);
    } else {
        // ---- convert job ----
        int idx = (blockIdx.x - 256) * 256 + threadIdx.x;   // one thread = 8 floats
        if (idx >= CONV_ITEMS) return;
        const int utotal = USER_NUM * EMB / 8;
        const float4* src = (idx < utotal) ? ((const float4*)ue) + 2 * (size_t)idx
                                           : ((const float4*)ie) + 2 * (size_t)(idx - utotal);
        float4 a = src[0], b = src[1];
        __half2 h0 = __floats2half2_rn(a.x * HSCALE, a.y * HSCALE);
        __half2 h1 = __floats2half2_rn(a.z * HSCALE, a.w * HSCALE);
        __half2 h2 = __floats2half2_rn(b.x * HSCALE, b.y * HSCALE);
        __half2 h3 = __floats2half2_rn(b.z * HSCALE, b.w * HSCALE);
        uint4 pk = make_uint4(*(const unsigned*)&h0, *(const unsigned*)&h1,
                              *(const unsigned*)&h2, *(const unsigned*)&h3);
        ((uint4*)x0h)[idx] = pk;
    }
}

// ===========================================================================
// Build step 2: exclusive scan of 469 bucket counts (single block)
// ===========================================================================
__global__ void bucket_scan_kernel(const int* __restrict__ bcounts, int* __restrict__ bucket_off,
                                   int* __restrict__ bcursor, int* __restrict__ row_ptr, int nnz) {
    __shared__ int lds[512];
    int t = threadIdx.x;
    int v = (t < NB) ? bcounts[t] : 0;
    lds[t] = v;
    __syncthreads();
    for (int off = 1; off < 512; off <<= 1) {
        int add = (t >= off) ? lds[t - off] : 0;
        __syncthreads();
        lds[t] += add;
        __syncthreads();
    }
    if (t < NB) {
        int ex = lds[t] - v;
        bucket_off[t] = ex;
        bcursor[t]    = ex;
    }
    if (t == 0) { bucket_off[NB] = nnz; row_ptr[NNODE] = nnz; }
}

// ===========================================================================
// Build step 3: bin edges into buckets (one global atomic per block,bucket;
// sequential line-friendly writes). Vectorized int4/float4 input reads.
// tmp packs {col | row_local<<17, val_bits}.
// ===========================================================================
__global__ void phase1_kernel(const int* __restrict__ rows, const int* __restrict__ cols,
                              const float* __restrict__ vals, int* __restrict__ bcursor,
                              int2* __restrict__ tmp, int nnz) {
    __shared__ int h[NB];
    __shared__ int base[NB];
    int t = threadIdx.x;
    for (int i = t; i < NB; i += 256) h[i] = 0;
    __syncthreads();
    int lo = blockIdx.x * P1_CHUNK;
    int hi = lo + P1_CHUNK; if (hi > nnz) hi = nnz;
    int n4 = (hi - lo) >> 2;                    // lo is 16B-aligned (P1_CHUNK%4==0)
    const int4*   rows4 = (const int4*)(rows + lo);
    const int4*   cols4 = (const int4*)(cols + lo);
    const float4* vals4 = (const float4*)(vals + lo);

    for (int i = t; i < n4; i += 256) {
        int4 r = rows4[i];
        atomicAdd(&h[r.x >> 8], 1);
        atomicAdd(&h[r.y >> 8], 1);
        atomicAdd(&h[r.z >> 8], 1);
        atomicAdd(&h[r.w >> 8], 1);
    }
    for (int i = lo + (n4 << 2) + t; i < hi; i += 256)
        atomicAdd(&h[rows[i] >> 8], 1);
    __syncthreads();
    for (int i = t; i < NB; i += 256) {
        int c = h[i];
        base[i] = c ? atomicAdd(&bcursor[i], c) : 0;
        h[i] = 0;
    }
    __syncthreads();
    for (int i = t; i < n4; i += 256) {
        int4 r = rows4[i];
        int4 c = cols4[i];
        float4 v = vals4[i];
        {
            int b = r.x >> 8; int loc = atomicAdd(&h[b], 1);
            tmp[base[b] + loc] = make_int2(c.x | ((r.x & 255) << 17), __float_as_int(v.x));
        }
        {
            int b = r.y >> 8; int loc = atomicAdd(&h[b], 1);
            tmp[base[b] + loc] = make_int2(c.y | ((r.y & 255) << 17), __float_as_int(v.y));
        }
        {
            int b = r.z >> 8; int loc = atomicAdd(&h[b], 1);
            tmp[base[b] + loc] = make_int2(c.z | ((r.z & 255) << 17), __float_as_int(v.z));
        }
        {
            int b = r.w >> 8; int loc = atomicAdd(&h[b], 1);
            tmp[base[b] + loc] = make_int2(c.w | ((r.w & 255) << 17), __float_as_int(v.w));
        }
    }
    for (int i = lo + (n4 << 2) + t; i < hi; i += 256) {
        int r = rows[i];
        int b = r >> 8;
        int loc = atomicAdd(&h[b], 1);
        tmp[base[b] + loc] = make_int2(cols[i] | ((r & 255) << 17), __float_as_int(vals[i]));
    }
}

// ===========================================================================
// Build step 4: one block per bucket, exact per-row counts + scan -> row_ptr;
// LDS cursors place edges into final CSR. 1024 threads/block: the two
// bucket passes were latency-limited at 256 threads (469 blocks = 23% of
// resident thread capacity); 4x threads cuts per-block pass latency ~4x.
// ===========================================================================
__global__ void phase2_kernel(const int2* __restrict__ tmp, const int* __restrict__ bucket_off,
                              int* __restrict__ row_ptr, int2* __restrict__ edges) {
    __shared__ int hist[256];
    __shared__ int scan[256];
    __shared__ int cur[256];
    int b = blockIdx.x;
    int t = threadIdx.x;               // 0..1023
    int row0  = b << 8;
    int nrows = NNODE - row0; if (nrows > 256) nrows = 256;
    int start = bucket_off[b];
    int end   = bucket_off[b + 1];
    if (t < 256) hist[t] = 0;
    __syncthreads();
    for (int j = start + t; j < end; j += 1024)
        atomicAdd(&hist[tmp[j].x >> 17], 1);
    __syncthreads();
    int v = 0;
    if (t < 256) { v = hist[t]; scan[t] = v; }
    __syncthreads();
    for (int off = 1; off < 256; off <<= 1) {
        int add = 0;
        if (t < 256 && t >= off) add = scan[t - off];
        __syncthreads();
        if (t < 256) scan[t] += add;
        __syncthreads();
    }
    if (t < 256) {
        int ex = scan[t] - v + start;  // exclusive prefix + bucket base
        if (t < nrows) row_ptr[row0 + t] = ex;
        cur[t] = ex;
    }
    __syncthreads();
    for (int j = start + t; j < end; j += 1024) {
        int2 e  = tmp[j];
        int rl  = e.x >> 17;
        int pos = atomicAdd(&cur[rl], 1);
        edges[pos] = make_int2(e.x & 0x1FFFF, e.y);
    }
}

// ===========================================================================
// CSR SpMM (all layers fp16-gather, 128B rows = 1 L2 transaction per edge):
// wave owns 4 rows; lane group g (16 lanes) owns row r0+g; lane c=(lane&15)
// holds dims [4c,4c+4). (R3 configuration: one block per 16 rows; the R4
// persistent-wave variant regressed -10us and is reverted.)
//   Gathered values are pre-scaled by HSCALE, so acc is scaled; layers 1/2
//   write acc packed to fp16 directly (identical path).
//   FINAL layer: gather y2h; read own-row y1h+y2h sequentially;
//   out = (y1h + y2h + acc) * HINV / 3   (single fp32 write pass).
// 16-edge chunks: most rows (deg~10-14) complete in ONE iteration with 16
// gathers in flight -> max memory-level parallelism per wave.
// ===========================================================================
__device__ __forceinline__ void load16(long long ev[16], const int2* __restrict__ edges,
                                       int sg, int eg, int j) {
    #pragma unroll
    for (int u = 0; u < 16; ++u) {
        int i = sg + j + u;
        ev[u] = (i < eg) ? *(const long long*)(edges + i) : 0LL;
    }
}

__device__ __forceinline__ float4 unpack_half4(uint2 gv) {
    float2 a = __half22float2(*(const __half2*)&gv.x);
    float2 b = __half22float2(*(const __half2*)&gv.y);
    return make_float4(a.x, a.y, b.x, b.y);
}

template <bool FINAL>
__launch_bounds__(256)
__global__ void spmm_kernel(const ushort* __restrict__ xh,
                            const int* __restrict__ row_ptr, const int2* __restrict__ edges,
                            ushort* __restrict__ yh,
                            const ushort* __restrict__ y1h_own, float* __restrict__ out) {
    int wave = (blockIdx.x * blockDim.x + threadIdx.x) >> 6;
    int lane = threadIdx.x & 63;
    int r0 = wave << 2;                    // 4 rows per wave; NNODE % 4 == 0
    if (r0 >= NNODE) return;
    int g = lane >> 4;                     // which of the 4 rows
    int c = lane & 15;                     // which uint2 chunk of the row

    int rp = 0;
    if (lane < 5) rp = row_ptr[r0 + lane];
    int p0 = __builtin_amdgcn_readlane(rp, 0);
    int p1 = __builtin_amdgcn_readlane(rp, 1);
    int p2 = __builtin_amdgcn_readlane(rp, 2);
    int p3 = __builtin_amdgcn_readlane(rp, 3);
    int p4 = __builtin_amdgcn_readlane(rp, 4);

    int sg = (g == 0) ? p0 : (g == 1) ? p1 : (g == 2) ? p2 : p3;   // row start
    int eg = (g == 0) ? p1 : (g == 1) ? p2 : (g == 2) ? p3 : p4;   // row end
    int maxd = max(max(p1 - p0, p2 - p1), max(p3 - p2, p4 - p3));  // wave loop bound

    float4 acc = make_float4(0.f, 0.f, 0.f, 0.f);

    for (int j = 0; j < maxd; j += 16) {
        long long ev[16];
        load16(ev, edges, sg, eg, j);
        #pragma unroll
        for (int u = 0; u < 16; ++u) {
            int   col = (int)(unsigned)ev[u];
            float v   = __int_as_float((int)(ev[u] >> 32));
            uint2 hv = ((const uint2*)(xh + (size_t)col * EMB))[c];
            float4 gv = unpack_half4(hv);
            acc.x += v * gv.x; acc.y += v * gv.y;
            acc.z += v * gv.z; acc.w += v * gv.w;
        }
    }

    int row = r0 + g;
    size_t oh = (size_t)row * EMB + (size_t)c * 4;   // element offset

    if (!FINAL) {
        // acc is already scaled (gathered values were pre-scaled)
        __half2 h0 = __floats2half2_rn(acc.x, acc.y);
        __half2 h1 = __floats2half2_rn(acc.z, acc.w);
        uint2 pk = make_uint2(*(const unsigned*)&h0, *(const unsigned*)&h1);
        *(uint2*)(yh + oh) = pk;
    } else {
        // acc == y3 * HSCALE; own-row y1,y2 (scaled fp16) read sequentially
        uint2 o1 = *(const uint2*)(y1h_own + oh);
        uint2 o2 = *(const uint2*)(xh + oh);
        float4 y1v = unpack_half4(o1);
        float4 y2v = unpack_half4(o2);
        const float s = HINV / 3.0f;
        float4 t;
        t.x = (y1v.x + y2v.x + acc.x) * s;
        t.y = (y1v.y + y2v.y + acc.y) * s;
        t.z = (y1v.z + y2v.z + acc.z) * s;
        t.w = (y1v.w + y2v.w + acc.w) * s;
        *(float4*)(out + oh) = t;
    }
}

// ===========================================================================
// Fallback (atomic path) in case ws_size is too small for CSR arrays
// ===========================================================================
__global__ void init_kernel(const float* __restrict__ user_emb, const float* __restrict__ item_emb,
                            float* __restrict__ x, float* __restrict__ out) {
    int idx = blockIdx.x * blockDim.x + threadIdx.x;
    const int total = NNODE * EMB / 4;
    if (idx >= total) return;
    const int user_total = USER_NUM * EMB / 4;
    float4 v = (idx < user_total) ? ((const float4*)user_emb)[idx]
                                  : ((const float4*)item_emb)[idx - user_total];
    ((float4*)x)[idx]   = v;
    ((float4*)out)[idx] = make_float4(0.f, 0.f, 0.f, 0.f);
}

__global__ void scatter_kernel(const float* __restrict__ x, float* __restrict__ y,
                               const float* __restrict__ vals, const int* __restrict__ rows,
                               const int* __restrict__ cols, int nnz) {
    int tid = blockIdx.x * blockDim.x + threadIdx.x;
    int e = tid >> 4;
    if (e >= nnz) return;
    int c = tid & 15;
    int r = rows[e], col = cols[e];
    float v = vals[e];
    float4 xv = ((const float4*)(x + (size_t)col * EMB))[c];
    float* dst = y + (size_t)r * EMB + (size_t)c * 4;
    atomicAdd(dst + 0, xv.x * v);
    atomicAdd(dst + 1, xv.y * v);
    atomicAdd(dst + 2, xv.z * v);
    atomicAdd(dst + 3, xv.w * v);
}

__global__ void accum_kernel(float* __restrict__ out, const float* __restrict__ y, float scale) {
    int idx = blockIdx.x * blockDim.x + threadIdx.x;
    const int total = NNODE * EMB / 4;
    if (idx >= total) return;
    float4 o = ((float4*)out)[idx];
    float4 a = ((const float4*)y)[idx];
    o.x = (o.x + a.x) * scale; o.y = (o.y + a.y) * scale;
    o.z = (o.z + a.z) * scale; o.w = (o.w + a.w) * scale;
    ((float4*)out)[idx] = o;
}

extern "C" void kernel_launch(void* const* d_in, const int* in_sizes, int n_in,
                              void* d_out, int out_size, void* d_ws, size_t ws_size,
                              hipStream_t stream) {
    const float* user_emb = (const float*)d_in[0];
    const float* item_emb = (const float*)d_in[1];
    const float* vals     = (const float*)d_in[2];
    const int*   rows     = (const int*)d_in[3];
    const int*   cols     = (const int*)d_in[4];
    const int    nnz      = in_sizes[2];

    float* out = (float*)d_out;

    const size_t embN   = (size_t)NNODE * EMB;        // 7,680,000 floats
    const size_t rp_pad = 120064;                     // NNODE+1 rounded up (8B-align after)

    // Persistent ws layout (unchanged footprint):
    //   bufA: embN floats | bufB: embN floats | row_ptr: rp_pad ints | edges: nnz int2
    // Build-time aliases (dead before their host buffer is written):
    //   tmp (nnz int2) -> front of bufA; bcounts/bucket_off/bcursor -> front of bufB
    // Runtime aliases:
    //   y1h (embN halves) + y2h (embN halves) occupy exactly bufA.
    //   x0h (embN halves) occupies the BACK half of bufB (clear of the 6KB
    //   build aliases at bufB's front and of row_ptr which starts after bufB).
    size_t need = (2 * embN + rp_pad) * 4 + (size_t)nnz * 8;

    if (ws_size >= need) {
        float* bufA    = (float*)d_ws;
        float* bufB    = bufA + embN;
        int*   row_ptr = (int*)(bufB + embN);
        int2*  edges   = (int2*)(row_ptr + rp_pad);

        int2* tmp        = (int2*)bufA;
        int*  bcounts    = (int*)bufB;
        int*  bucket_off = bcounts + 512;       // NB+1 used
        int*  bcursor    = bucket_off + 512;

        ushort* y1h = (ushort*)bufA;            // embN halves = 15.36 MB
        ushort* y2h = y1h + embN;               // 128B-aligned (embN*2 % 128 == 0)
        ushort* x0h = ((ushort*)bufB) + embN;   // back half of bufB, 15.36 MB

        // --- build CSR (two-pass LDS-binned counting sort), convert fused ---
        hipMemsetAsync(bcounts, 0, NB * sizeof(int), stream);
        convhist_kernel<<<256 + CONV_BLOCKS, 256, 0, stream>>>(user_emb, item_emb, x0h,
                                                               rows, bcounts, nnz);
        bucket_scan_kernel<<<1, 512, 0, stream>>>(bcounts, bucket_off, bcursor, row_ptr, nnz);
        phase1_kernel<<<(nnz + P1_CHUNK - 1) / P1_CHUNK, 256, 0, stream>>>(rows, cols, vals, bcursor, tmp, nnz);
        phase2_kernel<<<NB, 1024, 0, stream>>>(tmp, bucket_off, row_ptr, edges);

        // --- 3 propagation layers (identical fp16-gather kernels) ---
        const int nwaves = NNODE / 4;                      // 4 rows per wave
        const int blocks = (nwaves * 64 + 255) / 256;      // 4 waves per block
        spmm_kernel<false><<<blocks, 256, 0, stream>>>(x0h, row_ptr, edges, y1h, nullptr, nullptr);
        spmm_kernel<false><<<blocks, 256, 0, stream>>>(y1h, row_ptr, edges, y2h, nullptr, nullptr);
        spmm_kernel<true ><<<blocks, 256, 0, stream>>>(y2h, row_ptr, edges, nullptr, y1h, out);
    } else {
        // fallback: atomic scatter path
        float* x = (float*)d_ws;
        float* y = x + embN;
        const size_t emb_bytes = embN * sizeof(float);
        {
            int total = NNODE * EMB / 4;
            init_kernel<<<(total + 255) / 256, 256, 0, stream>>>(user_emb, item_emb, x, out);
        }
        for (int layer = 0; layer < 3; ++layer) {
            hipMemsetAsync(y, 0, emb_bytes, stream);
            long long threads = (long long)nnz * 16;
            scatter_kernel<<<(int)((threads + 255) / 256), 256, 0, stream>>>(x, y, vals, rows, cols, nnz);
            int total = NNODE * EMB / 4;
            accum_kernel<<<(total + 255) / 256, 256, 0, stream>>>(out, y, layer < 2 ? 1.0f : (1.0f / 3.0f));
            float* t = x; x = y; y = t;
        }
    }
}

// Round 6
// 208.774 us; speedup vs baseline: 1.1836x; 1.0740x over previous
//
#include <hip/hip_runtime.h>
#include <hip/hip_fp16.h>

#define USER_NUM 80000
#define ITEM_NUM 40000
#define NNODE (USER_NUM + ITEM_NUM)
#define EMB 64
#define NB 469            // ceil(NNODE / 256) buckets of 256 rows
#define P1_CHUNK 4096

// fp16 intermediate scaling: typical y ~ 1e-4 would be fp16-denormal; scale by
// 2^13 (exact) so stored magnitudes land in the normal range. Max |x|*S ~ 71.
#define HSCALE 8192.0f
#define HINV   (1.0f / 8192.0f)

// ===========================================================================
// Fused step 0 + build step 1 (independent jobs, disjoint block ranges):
//   blocks [0,256):   coarse histogram of row>>8 (LDS-aggregated, int4 loads)
//   blocks [256,...): convert fp32 embeddings -> scaled fp16 table x0h
// Overlaps the ~10us convert under the hist instead of serializing.
// ===========================================================================
#define CONV_ITEMS (NNODE * EMB / 8)                 // 960000 (8 floats/thread)
#define CONV_BLOCKS ((CONV_ITEMS + 255) / 256)       // 3750

__global__ void convhist_kernel(const float* __restrict__ ue, const float* __restrict__ ie,
                                ushort* __restrict__ x0h,
                                const int* __restrict__ rows, int* __restrict__ bcounts,
                                int nnz) {
    __shared__ int h[NB];
    if (blockIdx.x < 256) {
        // ---- histogram job ----
        for (int i = threadIdx.x; i < NB; i += 256) h[i] = 0;
        __syncthreads();
        int nq = nnz >> 2;
        int stride = 256 * 256;
        for (int i = blockIdx.x * 256 + threadIdx.x; i < nq; i += stride) {
            int4 r = ((const int4*)rows)[i];
            atomicAdd(&h[r.x >> 8], 1);
            atomicAdd(&h[r.y >> 8], 1);
            atomicAdd(&h[r.z >> 8], 1);
            atomicAdd(&h[r.w >> 8], 1);
        }
        if (blockIdx.x == 0) {
            for (int i = (nq << 2) + threadIdx.x; i < nnz; i += 256)
                atomicAdd(&h[rows[i] >> 8], 1);
        }
        __syncthreads();
        for (int i = threadIdx.x; i < NB; i += 256)
            if (h[i]) atomicAdd(&bcounts[i], h[i]);
    } else {
        // ---- convert job ----
        int idx = (blockIdx.x - 256) * 256 + threadIdx.x;   // one thread = 8 floats
        if (idx >= CONV_ITEMS) return;
        const int utotal = USER_NUM * EMB / 8;
        const float4* src = (idx < utotal) ? ((const float4*)ue) + 2 * (size_t)idx
                                           : ((const float4*)ie) + 2 * (size_t)(idx - utotal);
        float4 a = src[0], b = src[1];
        __half2 h0 = __floats2half2_rn(a.x * HSCALE, a.y * HSCALE);
        __half2 h1 = __floats2half2_rn(a.z * HSCALE, a.w * HSCALE);
        __half2 h2 = __floats2half2_rn(b.x * HSCALE, b.y * HSCALE);
        __half2 h3 = __floats2half2_rn(b.z * HSCALE, b.w * HSCALE);
        uint4 pk = make_uint4(*(const unsigned*)&h0, *(const unsigned*)&h1,
                              *(const unsigned*)&h2, *(const unsigned*)&h3);
        ((uint4*)x0h)[idx] = pk;
    }
}

// ===========================================================================
// Build step 2: exclusive scan of 469 bucket counts (single block)
// ===========================================================================
__global__ void bucket_scan_kernel(const int* __restrict__ bcounts, int* __restrict__ bucket_off,
                                   int* __restrict__ bcursor, int* __restrict__ row_ptr, int nnz) {
    __shared__ int lds[512];
    int t = threadIdx.x;
    int v = (t < NB) ? bcounts[t] : 0;
    lds[t] = v;
    __syncthreads();
    for (int off = 1; off < 512; off <<= 1) {
        int add = (t >= off) ? lds[t - off] : 0;
        __syncthreads();
        lds[t] += add;
        __syncthreads();
    }
    if (t < NB) {
        int ex = lds[t] - v;
        bucket_off[t] = ex;
        bcursor[t]    = ex;
    }
    if (t == 0) { bucket_off[NB] = nnz; row_ptr[NNODE] = nnz; }
}

// ===========================================================================
// Build step 3: bin edges into buckets (one global atomic per block,bucket;
// sequential line-friendly writes). Vectorized int4/float4 input reads.
// tmp packs {col | row_local<<17, val_bits}.
// ===========================================================================
__global__ void phase1_kernel(const int* __restrict__ rows, const int* __restrict__ cols,
                              const float* __restrict__ vals, int* __restrict__ bcursor,
                              int2* __restrict__ tmp, int nnz) {
    __shared__ int h[NB];
    __shared__ int base[NB];
    int t = threadIdx.x;
    for (int i = t; i < NB; i += 256) h[i] = 0;
    __syncthreads();
    int lo = blockIdx.x * P1_CHUNK;
    int hi = lo + P1_CHUNK; if (hi > nnz) hi = nnz;
    int n4 = (hi - lo) >> 2;                    // lo is 16B-aligned (P1_CHUNK%4==0)
    const int4*   rows4 = (const int4*)(rows + lo);
    const int4*   cols4 = (const int4*)(cols + lo);
    const float4* vals4 = (const float4*)(vals + lo);

    for (int i = t; i < n4; i += 256) {
        int4 r = rows4[i];
        atomicAdd(&h[r.x >> 8], 1);
        atomicAdd(&h[r.y >> 8], 1);
        atomicAdd(&h[r.z >> 8], 1);
        atomicAdd(&h[r.w >> 8], 1);
    }
    for (int i = lo + (n4 << 2) + t; i < hi; i += 256)
        atomicAdd(&h[rows[i] >> 8], 1);
    __syncthreads();
    for (int i = t; i < NB; i += 256) {
        int c = h[i];
        base[i] = c ? atomicAdd(&bcursor[i], c) : 0;
        h[i] = 0;
    }
    __syncthreads();
    for (int i = t; i < n4; i += 256) {
        int4 r = rows4[i];
        int4 c = cols4[i];
        float4 v = vals4[i];
        {
            int b = r.x >> 8; int loc = atomicAdd(&h[b], 1);
            tmp[base[b] + loc] = make_int2(c.x | ((r.x & 255) << 17), __float_as_int(v.x));
        }
        {
            int b = r.y >> 8; int loc = atomicAdd(&h[b], 1);
            tmp[base[b] + loc] = make_int2(c.y | ((r.y & 255) << 17), __float_as_int(v.y));
        }
        {
            int b = r.z >> 8; int loc = atomicAdd(&h[b], 1);
            tmp[base[b] + loc] = make_int2(c.z | ((r.z & 255) << 17), __float_as_int(v.z));
        }
        {
            int b = r.w >> 8; int loc = atomicAdd(&h[b], 1);
            tmp[base[b] + loc] = make_int2(c.w | ((r.w & 255) << 17), __float_as_int(v.w));
        }
    }
    for (int i = lo + (n4 << 2) + t; i < hi; i += 256) {
        int r = rows[i];
        int b = r >> 8;
        int loc = atomicAdd(&h[b], 1);
        tmp[base[b] + loc] = make_int2(cols[i] | ((r & 255) << 17), __float_as_int(vals[i]));
    }
}

// ===========================================================================
// Build step 4: one block per bucket, exact per-row counts + scan -> row_ptr;
// LDS cursors place edges into final CSR. 1024 threads/block.
// ===========================================================================
__global__ void phase2_kernel(const int2* __restrict__ tmp, const int* __restrict__ bucket_off,
                              int* __restrict__ row_ptr, int2* __restrict__ edges) {
    __shared__ int hist[256];
    __shared__ int scan[256];
    __shared__ int cur[256];
    int b = blockIdx.x;
    int t = threadIdx.x;               // 0..1023
    int row0  = b << 8;
    int nrows = NNODE - row0; if (nrows > 256) nrows = 256;
    int start = bucket_off[b];
    int end   = bucket_off[b + 1];
    if (t < 256) hist[t] = 0;
    __syncthreads();
    for (int j = start + t; j < end; j += 1024)
        atomicAdd(&hist[tmp[j].x >> 17], 1);
    __syncthreads();
    int v = 0;
    if (t < 256) { v = hist[t]; scan[t] = v; }
    __syncthreads();
    for (int off = 1; off < 256; off <<= 1) {
        int add = 0;
        if (t < 256 && t >= off) add = scan[t - off];
        __syncthreads();
        if (t < 256) scan[t] += add;
        __syncthreads();
    }
    if (t < 256) {
        int ex = scan[t] - v + start;  // exclusive prefix + bucket base
        if (t < nrows) row_ptr[row0 + t] = ex;
        cur[t] = ex;
    }
    __syncthreads();
    for (int j = start + t; j < end; j += 1024) {
        int2 e  = tmp[j];
        int rl  = e.x >> 17;
        int pos = atomicAdd(&cur[rl], 1);
        edges[pos] = make_int2(e.x & 0x1FFFF, e.y);
    }
}

// ===========================================================================
// CSR SpMM (fp16 tables, 128B rows): WAVE OWNS 8 ROWS, 8-lane groups, uint4
// (16B) gathers. One gather instruction now moves 1KB (8 x 128B segments) vs
// the previous 512B (4 segments) -- targeting the VMEM request-rate limit
// identified in R1-R5 (spmm well below stream BW with low VALUBusy).
// Lane layout: group g = lane>>3 owns row r0+g; lane c = lane&7 holds dims
// [8c, 8c+8). Unroll 8 edges (maxd over 8 rows ~ 17 -> ~2.6 iters, modest
// padding waste, 8 gathers in flight per wave).
//   non-FINAL: write acc (pre-scaled) packed to fp16 (uint4 = 16B/lane).
//   FINAL:     gather y2h; read own-row y1h+y2h sequentially;
//              out = (y1h + y2h + acc) * HINV / 3 (two float4 stores/lane).
// ===========================================================================
__device__ __forceinline__ float4 unpack_half4(uint2 gv) {
    float2 a = __half22float2(*(const __half2*)&gv.x);
    float2 b = __half22float2(*(const __half2*)&gv.y);
    return make_float4(a.x, a.y, b.x, b.y);
}

template <bool FINAL>
__launch_bounds__(256)
__global__ void spmm_kernel(const ushort* __restrict__ xh,
                            const int* __restrict__ row_ptr, const int2* __restrict__ edges,
                            ushort* __restrict__ yh,
                            const ushort* __restrict__ y1h_own, float* __restrict__ out) {
    int wave = (blockIdx.x * blockDim.x + threadIdx.x) >> 6;
    int lane = threadIdx.x & 63;
    int r0 = wave << 3;                    // 8 rows per wave; NNODE % 8 == 0
    if (r0 >= NNODE) return;
    int g = lane >> 3;                     // which of the 8 rows (0..7)
    int c = lane & 7;                      // which uint4 chunk (16B) of the row

    int rp = 0;
    if (lane < 9) rp = row_ptr[r0 + lane];
    int p0 = __builtin_amdgcn_readlane(rp, 0);
    int p1 = __builtin_amdgcn_readlane(rp, 1);
    int p2 = __builtin_amdgcn_readlane(rp, 2);
    int p3 = __builtin_amdgcn_readlane(rp, 3);
    int p4 = __builtin_amdgcn_readlane(rp, 4);
    int p5 = __builtin_amdgcn_readlane(rp, 5);
    int p6 = __builtin_amdgcn_readlane(rp, 6);
    int p7 = __builtin_amdgcn_readlane(rp, 7);
    int p8 = __builtin_amdgcn_readlane(rp, 8);

    int sg = (g < 4) ? ((g < 2) ? (g == 0 ? p0 : p1) : (g == 2 ? p2 : p3))
                     : ((g < 6) ? (g == 4 ? p4 : p5) : (g == 6 ? p6 : p7));
    int eg = (g < 4) ? ((g < 2) ? (g == 0 ? p1 : p2) : (g == 2 ? p3 : p4))
                     : ((g < 6) ? (g == 4 ? p5 : p6) : (g == 6 ? p7 : p8));
    int maxd = max(max(max(p1 - p0, p2 - p1), max(p3 - p2, p4 - p3)),
                   max(max(p5 - p4, p6 - p5), max(p7 - p6, p8 - p7)));

    float4 acc0 = make_float4(0.f, 0.f, 0.f, 0.f);
    float4 acc1 = make_float4(0.f, 0.f, 0.f, 0.f);

    for (int j = 0; j < maxd; j += 8) {
        long long ev[8];
        #pragma unroll
        for (int u = 0; u < 8; ++u) {
            int i = sg + j + u;
            ev[u] = (i < eg) ? *(const long long*)(edges + i) : 0LL;
        }
        #pragma unroll
        for (int u = 0; u < 8; ++u) {
            int   col = (int)(unsigned)ev[u];
            float v   = __int_as_float((int)(ev[u] >> 32));
            uint4 hv = ((const uint4*)(xh + (size_t)col * EMB))[c];
            float2 a0 = __half22float2(*(const __half2*)&hv.x);
            float2 a1 = __half22float2(*(const __half2*)&hv.y);
            float2 a2 = __half22float2(*(const __half2*)&hv.z);
            float2 a3 = __half22float2(*(const __half2*)&hv.w);
            acc0.x += v * a0.x; acc0.y += v * a0.y;
            acc0.z += v * a1.x; acc0.w += v * a1.y;
            acc1.x += v * a2.x; acc1.y += v * a2.y;
            acc1.z += v * a3.x; acc1.w += v * a3.y;
        }
    }

    int row = r0 + g;
    size_t oh = (size_t)row * EMB + (size_t)c * 8;   // element offset (8 per lane)

    if (!FINAL) {
        // acc is already scaled (gathered values were pre-scaled)
        __half2 h0 = __floats2half2_rn(acc0.x, acc0.y);
        __half2 h1 = __floats2half2_rn(acc0.z, acc0.w);
        __half2 h2 = __floats2half2_rn(acc1.x, acc1.y);
        __half2 h3 = __floats2half2_rn(acc1.z, acc1.w);
        uint4 pk = make_uint4(*(const unsigned*)&h0, *(const unsigned*)&h1,
                              *(const unsigned*)&h2, *(const unsigned*)&h3);
        *(uint4*)(yh + oh) = pk;
    } else {
        // acc == y3 * HSCALE; own-row y1,y2 (scaled fp16) read sequentially
        uint4 o1 = *(const uint4*)(y1h_own + oh);
        uint4 o2 = *(const uint4*)(xh + oh);
        float4 y1a = unpack_half4(make_uint2(o1.x, o1.y));
        float4 y1b = unpack_half4(make_uint2(o1.z, o1.w));
        float4 y2a = unpack_half4(make_uint2(o2.x, o2.y));
        float4 y2b = unpack_half4(make_uint2(o2.z, o2.w));
        const float s = HINV / 3.0f;
        float4 ta, tb;
        ta.x = (y1a.x + y2a.x + acc0.x) * s;
        ta.y = (y1a.y + y2a.y + acc0.y) * s;
        ta.z = (y1a.z + y2a.z + acc0.z) * s;
        ta.w = (y1a.w + y2a.w + acc0.w) * s;
        tb.x = (y1b.x + y2b.x + acc1.x) * s;
        tb.y = (y1b.y + y2b.y + acc1.y) * s;
        tb.z = (y1b.z + y2b.z + acc1.z) * s;
        tb.w = (y1b.w + y2b.w + acc1.w) * s;
        *(float4*)(out + oh)     = ta;
        *(float4*)(out + oh + 4) = tb;
    }
}

// ===========================================================================
// Fallback (atomic path) in case ws_size is too small for CSR arrays
// ===========================================================================
__global__ void init_kernel(const float* __restrict__ user_emb, const float* __restrict__ item_emb,
                            float* __restrict__ x, float* __restrict__ out) {
    int idx = blockIdx.x * blockDim.x + threadIdx.x;
    const int total = NNODE * EMB / 4;
    if (idx >= total) return;
    const int user_total = USER_NUM * EMB / 4;
    float4 v = (idx < user_total) ? ((const float4*)user_emb)[idx]
                                  : ((const float4*)item_emb)[idx - user_total];
    ((float4*)x)[idx]   = v;
    ((float4*)out)[idx] = make_float4(0.f, 0.f, 0.f, 0.f);
}

__global__ void scatter_kernel(const float* __restrict__ x, float* __restrict__ y,
                               const float* __restrict__ vals, const int* __restrict__ rows,
                               const int* __restrict__ cols, int nnz) {
    int tid = blockIdx.x * blockDim.x + threadIdx.x;
    int e = tid >> 4;
    if (e >= nnz) return;
    int c = tid & 15;
    int r = rows[e], col = cols[e];
    float v = vals[e];
    float4 xv = ((const float4*)(x + (size_t)col * EMB))[c];
    float* dst = y + (size_t)r * EMB + (size_t)c * 4;
    atomicAdd(dst + 0, xv.x * v);
    atomicAdd(dst + 1, xv.y * v);
    atomicAdd(dst + 2, xv.z * v);
    atomicAdd(dst + 3, xv.w * v);
}

__global__ void accum_kernel(float* __restrict__ out, const float* __restrict__ y, float scale) {
    int idx = blockIdx.x * blockDim.x + threadIdx.x;
    const int total = NNODE * EMB / 4;
    if (idx >= total) return;
    float4 o = ((float4*)out)[idx];
    float4 a = ((const float4*)y)[idx];
    o.x = (o.x + a.x) * scale; o.y = (o.y + a.y) * scale;
    o.z = (o.z + a.z) * scale; o.w = (o.w + a.w) * scale;
    ((float4*)out)[idx] = o;
}

extern "C" void kernel_launch(void* const* d_in, const int* in_sizes, int n_in,
                              void* d_out, int out_size, void* d_ws, size_t ws_size,
                              hipStream_t stream) {
    const float* user_emb = (const float*)d_in[0];
    const float* item_emb = (const float*)d_in[1];
    const float* vals     = (const float*)d_in[2];
    const int*   rows     = (const int*)d_in[3];
    const int*   cols     = (const int*)d_in[4];
    const int    nnz      = in_sizes[2];

    float* out = (float*)d_out;

    const size_t embN   = (size_t)NNODE * EMB;        // 7,680,000 floats
    const size_t rp_pad = 120064;                     // NNODE+1 rounded up (8B-align after)

    // Persistent ws layout (unchanged footprint):
    //   bufA: embN floats | bufB: embN floats | row_ptr: rp_pad ints | edges: nnz int2
    // Build-time aliases (dead before their host buffer is written):
    //   tmp (nnz int2) -> front of bufA; bcounts/bucket_off/bcursor -> front of bufB
    // Runtime aliases:
    //   y1h (embN halves) + y2h (embN halves) occupy exactly bufA.
    //   x0h (embN halves) occupies the BACK half of bufB.
    size_t need = (2 * embN + rp_pad) * 4 + (size_t)nnz * 8;

    if (ws_size >= need) {
        float* bufA    = (float*)d_ws;
        float* bufB    = bufA + embN;
        int*   row_ptr = (int*)(bufB + embN);
        int2*  edges   = (int2*)(row_ptr + rp_pad);

        int2* tmp        = (int2*)bufA;
        int*  bcounts    = (int*)bufB;
        int*  bucket_off = bcounts + 512;       // NB+1 used
        int*  bcursor    = bucket_off + 512;

        ushort* y1h = (ushort*)bufA;            // embN halves = 15.36 MB
        ushort* y2h = y1h + embN;               // 128B-aligned (embN*2 % 128 == 0)
        ushort* x0h = ((ushort*)bufB) + embN;   // back half of bufB, 15.36 MB

        // --- build CSR (two-pass LDS-binned counting sort), convert fused ---
        hipMemsetAsync(bcounts, 0, NB * sizeof(int), stream);
        convhist_kernel<<<256 + CONV_BLOCKS, 256, 0, stream>>>(user_emb, item_emb, x0h,
                                                               rows, bcounts, nnz);
        bucket_scan_kernel<<<1, 512, 0, stream>>>(bcounts, bucket_off, bcursor, row_ptr, nnz);
        phase1_kernel<<<(nnz + P1_CHUNK - 1) / P1_CHUNK, 256, 0, stream>>>(rows, cols, vals, bcursor, tmp, nnz);
        phase2_kernel<<<NB, 1024, 0, stream>>>(tmp, bucket_off, row_ptr, edges);

        // --- 3 propagation layers (8 rows/wave, uint4 gathers) ---
        const int nwaves = NNODE / 8;                      // 8 rows per wave
        const int blocks = (nwaves * 64 + 255) / 256;      // 4 waves per block
        spmm_kernel<false><<<blocks, 256, 0, stream>>>(x0h, row_ptr, edges, y1h, nullptr, nullptr);
        spmm_kernel<false><<<blocks, 256, 0, stream>>>(y1h, row_ptr, edges, y2h, nullptr, nullptr);
        spmm_kernel<true ><<<blocks, 256, 0, stream>>>(y2h, row_ptr, edges, nullptr, y1h, out);
    } else {
        // fallback: atomic scatter path
        float* x = (float*)d_ws;
        float* y = x + embN;
        const size_t emb_bytes = embN * sizeof(float);
        {
            int total = NNODE * EMB / 4;
            init_kernel<<<(total + 255) / 256, 256, 0, stream>>>(user_emb, item_emb, x, out);
        }
        for (int layer = 0; layer < 3; ++layer) {
            hipMemsetAsync(y, 0, emb_bytes, stream);
            long long threads = (long long)nnz * 16;
            scatter_kernel<<<(int)((threads + 255) / 256), 256, 0, stream>>>(x, y, vals, rows, cols, nnz);
            int total = NNODE * EMB / 4;
            accum_kernel<<<(total + 255) / 256, 256, 0, stream>>>(out, y, layer < 2 ? 1.0f : (1.0f / 3.0f));
            float* t = x; x = y; y = t;
        }
    }
}